// Round 13
// baseline (710.880 us; speedup 1.0000x reference)
//
#include <hip/hip_runtime.h>
#include <hip/hip_bf16.h>

#define BATCH   256
#define NLAYERS 32
#define HID     1024
#define INTER   2816
#define BK      64

typedef __attribute__((ext_vector_type(8))) short bf16x8;
typedef __attribute__((ext_vector_type(4))) float f32x4;
typedef __attribute__((ext_vector_type(4))) int   i32x4;

__device__ __forceinline__ ushort f2bf(float f) {
  __hip_bfloat16 b = __float2bfloat16(f);   // RNE
  return *reinterpret_cast<ushort*>(&b);
}

__device__ __forceinline__ bf16x8 cvt8(f32x4 a, f32x4 b) {
  bf16x8 o;
  o[0] = (short)f2bf(a[0]); o[1] = (short)f2bf(a[1]);
  o[2] = (short)f2bf(a[2]); o[3] = (short)f2bf(a[3]);
  o[4] = (short)f2bf(b[0]); o[5] = (short)f2bf(b[1]);
  o[6] = (short)f2bf(b[2]); o[7] = (short)f2bf(b[3]);
  return o;
}

// ---------------------------------------------------------------------------
// Kernel 0: pack h (B,N,D) fp32 -> Xp[n][b][d] bf16 (contiguous per layer).
// UNCHANGED (measured ~10 us).
// ---------------------------------------------------------------------------
__global__ __launch_bounds__(256) void k_pack_v3(
    const float* __restrict__ h, ushort* __restrict__ Xp) {
  const int r    = blockIdx.x * 4 + (threadIdx.x >> 6);   // 0..8191 = b*32+n
  const int lane = threadIdx.x & 63;
  const int ro   = ((r & 31) * 256 + (r >> 5)) * 1024;    // out row = n*256+b
  const float* src = h + (size_t)r * 1024 + lane * 4;
  ushort* dst      = Xp + ro + lane * 4;
#pragma unroll
  for (int g = 0; g < 4; ++g) {
    f32x4 v = *(const f32x4*)(src + g * 256);
    ushort4 o;
    o.x = f2bf(v[0]); o.y = f2bf(v[1]); o.z = f2bf(v[2]); o.w = f2bf(v[3]);
    *(ushort4*)(dst + g * 256) = o;
  }
}

// ---------------------------------------------------------------------------
// Kernel 1: act = silu(X Wg^T)*(X Wu^T).  A-IN-REGISTERS design:
// block = 1024 thr = 16 waves; wave w owns batch rows [16w,16w+16) -> the
// full 256-row batch per block => weights still read from HBM exactly once.
// Per lane: full-K A row-fragment = 32 slabs x bf16x8 = 128 VGPR, loaded
// ONCE from Xp (static indices only; k-loop fully unrolled).  Per k-step the
// block stages ONLY 16 KB of weights (R4-proven 2-barrier + reg-prefetch +
// XOR-swizzle; 8 KB LDS single buffer); per wave-step: 8 ds_read_b128 +
// 8 MFMA, zero A-LDS traffic.  Two sequential 32-col passes reuse the A
// registers (grid 32*44=1408 -> A-prologue L2 traffic 2.8 MB/CU).
// NO XCD swizzle (R12: -11%).  __launch_bounds__(1024,8) -> VGPR<=256,
// 2 blocks/CU.
// ---------------------------------------------------------------------------
__global__ __launch_bounds__(1024, 8) void k_gateup_reg(
    const ushort* __restrict__ Xp, const float* __restrict__ Wg,
    const float* __restrict__ Wu, ushort* __restrict__ act) {
  const int bid   = blockIdx.x;               // 0..1407
  const int layer = bid / 44;
  const int i0    = (bid % 44) * 64;
  const int tid   = threadIdx.x;
  const int lane  = tid & 63;
  const int wave  = tid >> 6;                 // 0..15
  const int r16   = lane & 15;
  const int g4    = lane >> 4;

  __shared__ ushort Wl[64 * 64];              // 8 KB (64 rows x 64 bf16)

  // ---- A panel -> registers (once): row = 16*wave + r16, 32 slabs of K=32
  bf16x8 a[32];
  {
    const ushort* ap = Xp + ((size_t)layer * BATCH + wave * 16 + r16) * HID + g4 * 8;
#pragma unroll
    for (int s = 0; s < 32; ++s)
      a[s] = *(const bf16x8*)(ap + s * 32);
  }

  // W staging (threads 0..511): tile row = t>>3 (0..63: <32 Wg, >=32 Wu),
  // slot = t&7 (8-float granule); XOR swizzle proven 0-conflict (R4).
  const bool stg  = (tid < 512);
  const int  wrow = (tid & 511) >> 3;
  const int  wsl  = tid & 7;
  const int  wldst = wrow * 64 + ((wsl ^ (wrow & 7)) << 3);

#pragma unroll
  for (int pass = 0; pass < 2; ++pass) {
    const int ip = i0 + pass * 32;
    const float* wsrc = (wrow < 32 ? Wg + (size_t)(ip + wrow) * HID
                                   : Wu + (size_t)(ip + wrow - 32) * HID)
                        + (size_t)layer * INTER * HID + wsl * 8;
    f32x4 rw0, rw1;
    if (stg) { rw0 = *(const f32x4*)wsrc; rw1 = *(const f32x4*)(wsrc + 4); }

    f32x4 acc[2][2] = {};                     // [n][0=gate,1=up]

#pragma unroll
    for (int k = 0; k < 16; ++k) {
      __syncthreads();                        // Wl consumed by prev step
      if (stg) *(bf16x8*)&Wl[wldst] = cvt8(rw0, rw1);
      __syncthreads();                        // Wl ready
      if (k < 15 && stg) {                    // prefetch k+1 (in flight across MFMA)
        rw0 = *(const f32x4*)(wsrc + (k + 1) * 64);
        rw1 = *(const f32x4*)(wsrc + (k + 1) * 64 + 4);
      }
#pragma unroll
      for (int ks = 0; ks < 2; ++ks) {
        const int kg = ks * 4 + g4;
#pragma unroll
        for (int n = 0; n < 2; ++n) {
          const int rg_ = n * 16 + r16;       // gate row in tile
          const int ru_ = 32 + rg_;           // up row
          bf16x8 bg = *(bf16x8*)&Wl[rg_ * 64 + ((kg ^ (rg_ & 7)) << 3)];
          bf16x8 bu = *(bf16x8*)&Wl[ru_ * 64 + ((kg ^ (ru_ & 7)) << 3)];
          acc[n][0] = __builtin_amdgcn_mfma_f32_16x16x32_bf16(a[2 * k + ks], bg, acc[n][0], 0, 0, 0);
          acc[n][1] = __builtin_amdgcn_mfma_f32_16x16x32_bf16(a[2 * k + ks], bu, acc[n][1], 0, 0, 0);
        }
      }
    }

    // epilogue: silu(gate)*up. C/D: col=lane&15, row=g4*4+r; wave row base 16w
    const int r4 = g4 * 4;
#pragma unroll
    for (int n = 0; n < 2; ++n)
#pragma unroll
      for (int r = 0; r < 4; ++r) {
        float g = acc[n][0][r];
        float u = acc[n][1][r];
        float v = (g / (1.f + __expf(-g))) * u;
        int b = wave * 16 + r4 + r;
        int i = ip + n * 16 + r16;
        act[((size_t)layer * BATCH + b) * INTER + i] = f2bf(v);
      }
  }
}

// ---------------------------------------------------------------------------
// Kernel 2: out[b][layer][d] = act Wd^T.  R1 exact structure, natural block
// order (swizzle reverted per R12).  Measured ~65 us (at its roofline).
// ---------------------------------------------------------------------------
__global__ __launch_bounds__(512) void k_down_v3(
    const ushort* __restrict__ act, const float* __restrict__ Wd,
    float* __restrict__ out) {
  const int bid   = blockIdx.x;
  const int layer = bid / (HID / 64);
  const int dtile = bid % (HID / 64);
  const int d0    = dtile * 64;
  const int tid   = threadIdx.x;
  const int lane  = tid & 63;
  const int wave  = tid >> 6;
  const int wm    = wave >> 1;
  const int wn    = wave & 1;

  __shared__ ushort lds[BATCH * BK + 64 * BK];       // 40 KiB
  ushort* Al = lds;
  ushort* Wl = lds + BATCH * BK;

  f32x4 acc[4][2] = {};

  int aldst[4];
  const ushort* asrc[4];
#pragma unroll
  for (int r = 0; r < 4; ++r) {
    int g = tid + 512 * r;
    int arow = g >> 3, akc = g & 7;
    aldst[r] = arow * BK + ((akc ^ (arow & 7)) << 3);
    asrc[r] = act + ((size_t)layer * BATCH + arow) * INTER + akc * 8;
  }
  const int wrow = tid >> 3, wkc = tid & 7;
  const int wldst = wrow * BK + ((wkc ^ (wrow & 7)) << 3);
  const float* wsrc = Wd + (size_t)layer * HID * INTER + (size_t)(d0 + wrow) * INTER + wkc * 8;

  i32x4 ra[4];
  f32x4 rw[2];

#pragma unroll
  for (int r = 0; r < 4; ++r) ra[r] = *(const i32x4*)asrc[r];
  rw[0] = *(const f32x4*)wsrc; rw[1] = *(const f32x4*)(wsrc + 4);

  const int NK = INTER / BK;   // 44
  for (int k = 0; k < NK; ++k) {
    __syncthreads();
#pragma unroll
    for (int r = 0; r < 4; ++r) *(i32x4*)&Al[aldst[r]] = ra[r];
    *(bf16x8*)&Wl[wldst] = cvt8(rw[0], rw[1]);
    __syncthreads();

    if (k + 1 < NK) {
      int off = (k + 1) * BK;
#pragma unroll
      for (int r = 0; r < 4; ++r) ra[r] = *(const i32x4*)(asrc[r] + off);
      rw[0] = *(const f32x4*)(wsrc + off); rw[1] = *(const f32x4*)(wsrc + off + 4);
    }

#pragma unroll
    for (int ks = 0; ks < 2; ++ks) {
      const int kg = ks * 4 + (lane >> 4);
      bf16x8 af[4];
#pragma unroll
      for (int m = 0; m < 4; ++m) {
        int row = wm * 64 + m * 16 + (lane & 15);
        af[m] = *(bf16x8*)&Al[row * BK + ((kg ^ (row & 7)) << 3)];
      }
#pragma unroll
      for (int n = 0; n < 2; ++n) {
        int row = wn * 32 + n * 16 + (lane & 15);
        bf16x8 bw = *(bf16x8*)&Wl[row * BK + ((kg ^ (row & 7)) << 3)];
#pragma unroll
        for (int m = 0; m < 4; ++m)
          acc[m][n] = __builtin_amdgcn_mfma_f32_16x16x32_bf16(af[m], bw, acc[m][n], 0, 0, 0);
      }
    }
  }

  const int c16 = lane & 15;
  const int r4  = (lane >> 4) * 4;
#pragma unroll
  for (int m = 0; m < 4; ++m)
#pragma unroll
    for (int n = 0; n < 2; ++n)
#pragma unroll
      for (int r = 0; r < 4; ++r) {
        int b = wm * 64 + m * 16 + r4 + r;
        int d = d0 + wn * 32 + n * 16 + c16;
        out[(size_t)b * (NLAYERS * HID) + (size_t)layer * HID + d] = acc[m][n][r];
      }
}

extern "C" void kernel_launch(void* const* d_in, const int* in_sizes, int n_in,
                              void* d_out, int out_size, void* d_ws, size_t ws_size,
                              hipStream_t stream) {
  const float* h  = (const float*)d_in[0];
  const float* Wg = (const float*)d_in[1];
  const float* Wu = (const float*)d_in[2];
  const float* Wd = (const float*)d_in[3];
  float* out  = (float*)d_out;
  ushort* act = (ushort*)d_ws;                                   // 46.1 MB
  ushort* Xp  = (ushort*)d_ws + (size_t)NLAYERS * BATCH * INTER; // +16.8 MB

  hipLaunchKernelGGL(k_pack_v3, dim3(BATCH * NLAYERS / 4), dim3(256), 0, stream,
                     h, Xp);
  hipLaunchKernelGGL(k_gateup_reg, dim3(NLAYERS * (INTER / 64)), dim3(1024), 0, stream,
                     Xp, Wg, Wu, act);
  hipLaunchKernelGGL(k_down_v3, dim3(NLAYERS * (HID / 64)), dim3(512), 0, stream,
                     act, Wd, out);
}

// Round 14
// 543.845 us; speedup vs baseline: 1.3071x; 1.3071x over previous
//
#include <hip/hip_runtime.h>
#include <hip/hip_bf16.h>

#define BATCH   256
#define NLAYERS 32
#define HID     1024
#define INTER   2816
#define BK      64

typedef __attribute__((ext_vector_type(8))) short bf16x8;
typedef __attribute__((ext_vector_type(4))) float f32x4;
typedef __attribute__((ext_vector_type(4))) int   i32x4;

__device__ __forceinline__ ushort f2bf(float f) {
  __hip_bfloat16 b = __float2bfloat16(f);   // RNE
  return *reinterpret_cast<ushort*>(&b);
}

__device__ __forceinline__ bf16x8 cvt8(f32x4 a, f32x4 b) {
  bf16x8 o;
  o[0] = (short)f2bf(a[0]); o[1] = (short)f2bf(a[1]);
  o[2] = (short)f2bf(a[2]); o[3] = (short)f2bf(a[3]);
  o[4] = (short)f2bf(b[0]); o[5] = (short)f2bf(b[1]);
  o[6] = (short)f2bf(b[2]); o[7] = (short)f2bf(b[3]);
  return o;
}

// ---------------------------------------------------------------------------
// Kernel 0: h (B,N,D) fp32 -> Xp3 in MFMA-FRAGMENT ORDER:
// Xp3[layer][slab s(32)][mfrag f(16)][lane l(64)] : 8 bf16 of
// (row = f*16 + (l&15), k = s*32 + (l>>4)*8 .. +8).
// One wave per (layer,s,f): reads 2 f32x4/lane (gathered, whole-h read once),
// writes one coalesced 1KB fragment.  16384 waves.
// ---------------------------------------------------------------------------
__global__ __launch_bounds__(256) void k_pack_frag(
    const float* __restrict__ h, ushort* __restrict__ Xp3) {
  const int w     = blockIdx.x * 4 + (threadIdx.x >> 6);  // 0..16383
  const int lane  = threadIdx.x & 63;
  const int layer = w >> 9;          // 512 waves per layer
  const int s     = (w >> 4) & 31;
  const int f     = w & 15;
  const int b     = f * 16 + (lane & 15);
  const int d     = s * 32 + ((lane >> 4) << 3);
  const float* src = h + (size_t)b * (NLAYERS * HID) + (size_t)layer * HID + d;
  f32x4 lo = *(const f32x4*)src;
  f32x4 hi = *(const f32x4*)(src + 4);
  ushort* dst = Xp3 + (((size_t)layer * 32 + s) * 16 + f) * 512 + lane * 8;
  *(bf16x8*)dst = cvt8(lo, hi);
}

// ---------------------------------------------------------------------------
// Kernel 1: act = silu(X Wg^T)*(X Wu^T).  ZERO LDS, ZERO BARRIERS.
// Block = 512 thr = 8 independent waves; wave w: mt=w&1 (128 rows),
// colgroup w>>1 -> 16 inter cols; block covers 256 rows x 64 cols, so each
// weight line is read by exactly ONE block (HBM once; 2x mt-reuse is
// intra-block, concurrent, L2-served).
// Per slab (K=32): 8 coalesced 1KB A-frag loads (Xp3, L2/L3-resident) +
// 4 fp32 B loads (full-line-consuming gather) + 2 cvt8 + 16 MFMA.
// Explicit depth-1 software pipeline, named regs, all indices static after
// unroll (rule #20).  No sync points -> waves free-run; latency hidden by
// 8 waves/CU x ~12KB in flight each.  __launch_bounds__(512,2): VGPR<=256.
// ---------------------------------------------------------------------------
__global__ __launch_bounds__(512, 2) void k_gateup_frag(
    const ushort* __restrict__ Xp3, const float* __restrict__ Wg,
    const float* __restrict__ Wu, ushort* __restrict__ act) {
  const int bid   = blockIdx.x;             // 0..1407
  const int layer = bid / 44;
  const int cb    = bid % 44;
  const int tid   = threadIdx.x;
  const int lane  = tid & 63;
  const int w     = tid >> 6;               // 0..7
  const int mt    = w & 1;                  // 128-row half
  const int i0    = cb * 64 + (w >> 1) * 16;
  const int c16   = lane & 15;
  const int g4    = lane >> 4;

  // A fragments: abase + (s*16 + mf)*512 is a coalesced 1KB fragment
  const ushort* abase = Xp3 + (size_t)layer * (32 * 16 * 512)
                        + (size_t)(mt * 8) * 512 + lane * 8;
  // B: lane reads fp32 W[col=i0+c16][s*32 + g4*8 .. +8]  (lo/hi f32x4)
  const float* gbase = Wg + ((size_t)layer * INTER + i0 + c16) * HID + g4 * 8;
  const float* ubase = Wu + ((size_t)layer * INTER + i0 + c16) * HID + g4 * 8;

  f32x4 acc[8][2] = {};                     // [mfrag][0=gate,1=up]

  bf16x8 a0[8], a1[8];
  f32x4 g0lo, g0hi, u0lo, u0hi, g1lo, g1hi, u1lo, u1hi;

  // prologue: slab 0
#pragma unroll
  for (int mf = 0; mf < 8; ++mf) a0[mf] = *(const bf16x8*)(abase + mf * 512);
  g0lo = *(const f32x4*)(gbase);     g0hi = *(const f32x4*)(gbase + 4);
  u0lo = *(const f32x4*)(ubase);     u0hi = *(const f32x4*)(ubase + 4);

#pragma unroll
  for (int s = 0; s < 32; ++s) {
    if (s + 1 < 32) {                       // issue slab s+1 (in flight over MFMAs)
      const ushort* an = abase + (size_t)(s + 1) * 16 * 512;
#pragma unroll
      for (int mf = 0; mf < 8; ++mf) a1[mf] = *(const bf16x8*)(an + mf * 512);
      g1lo = *(const f32x4*)(gbase + (s + 1) * 32);
      g1hi = *(const f32x4*)(gbase + (s + 1) * 32 + 4);
      u1lo = *(const f32x4*)(ubase + (s + 1) * 32);
      u1hi = *(const f32x4*)(ubase + (s + 1) * 32 + 4);
    }
    bf16x8 bg = cvt8(g0lo, g0hi);
    bf16x8 bu = cvt8(u0lo, u0hi);
#pragma unroll
    for (int mf = 0; mf < 8; ++mf) {
      acc[mf][0] = __builtin_amdgcn_mfma_f32_16x16x32_bf16(a0[mf], bg, acc[mf][0], 0, 0, 0);
      acc[mf][1] = __builtin_amdgcn_mfma_f32_16x16x32_bf16(a0[mf], bu, acc[mf][1], 0, 0, 0);
    }
#pragma unroll
    for (int mf = 0; mf < 8; ++mf) a0[mf] = a1[mf];   // register renames
    g0lo = g1lo; g0hi = g1hi; u0lo = u1lo; u0hi = u1hi;
  }

  // epilogue: silu(gate)*up.  C/D map: col=lane&15, row=(lane>>4)*4+r
  const int r4 = g4 * 4;
#pragma unroll
  for (int mf = 0; mf < 8; ++mf)
#pragma unroll
    for (int r = 0; r < 4; ++r) {
      float g = acc[mf][0][r];
      float u = acc[mf][1][r];
      float v = (g / (1.f + __expf(-g))) * u;
      int b = mt * 128 + mf * 16 + r4 + r;
      act[((size_t)layer * BATCH + b) * INTER + i0 + c16] = f2bf(v);
    }
}

// ---------------------------------------------------------------------------
// Kernel 2: out[b][layer][d] = act Wd^T.  UNCHANGED R1 structure, natural
// block order (measured at its roofline, ~65 us).
// ---------------------------------------------------------------------------
__global__ __launch_bounds__(512) void k_down_v4(
    const ushort* __restrict__ act, const float* __restrict__ Wd,
    float* __restrict__ out) {
  const int bid   = blockIdx.x;
  const int layer = bid / (HID / 64);
  const int dtile = bid % (HID / 64);
  const int d0    = dtile * 64;
  const int tid   = threadIdx.x;
  const int lane  = tid & 63;
  const int wave  = tid >> 6;
  const int wm    = wave >> 1;
  const int wn    = wave & 1;

  __shared__ ushort lds[BATCH * BK + 64 * BK];       // 40 KiB
  ushort* Al = lds;
  ushort* Wl = lds + BATCH * BK;

  f32x4 acc[4][2] = {};

  int aldst[4];
  const ushort* asrc[4];
#pragma unroll
  for (int r = 0; r < 4; ++r) {
    int g = tid + 512 * r;
    int arow = g >> 3, akc = g & 7;
    aldst[r] = arow * BK + ((akc ^ (arow & 7)) << 3);
    asrc[r] = act + ((size_t)layer * BATCH + arow) * INTER + akc * 8;
  }
  const int wrow = tid >> 3, wkc = tid & 7;
  const int wldst = wrow * BK + ((wkc ^ (wrow & 7)) << 3);
  const float* wsrc = Wd + (size_t)layer * HID * INTER + (size_t)(d0 + wrow) * INTER + wkc * 8;

  i32x4 ra[4];
  f32x4 rw[2];

#pragma unroll
  for (int r = 0; r < 4; ++r) ra[r] = *(const i32x4*)asrc[r];
  rw[0] = *(const f32x4*)wsrc; rw[1] = *(const f32x4*)(wsrc + 4);

  const int NK = INTER / BK;   // 44
  for (int k = 0; k < NK; ++k) {
    __syncthreads();
#pragma unroll
    for (int r = 0; r < 4; ++r) *(i32x4*)&Al[aldst[r]] = ra[r];
    *(bf16x8*)&Wl[wldst] = cvt8(rw[0], rw[1]);
    __syncthreads();

    if (k + 1 < NK) {
      int off = (k + 1) * BK;
#pragma unroll
      for (int r = 0; r < 4; ++r) ra[r] = *(const i32x4*)(asrc[r] + off);
      rw[0] = *(const f32x4*)(wsrc + off); rw[1] = *(const f32x4*)(wsrc + off + 4);
    }

#pragma unroll
    for (int ks = 0; ks < 2; ++ks) {
      const int kg = ks * 4 + (lane >> 4);
      bf16x8 af[4];
#pragma unroll
      for (int m = 0; m < 4; ++m) {
        int row = wm * 64 + m * 16 + (lane & 15);
        af[m] = *(bf16x8*)&Al[row * BK + ((kg ^ (row & 7)) << 3)];
      }
#pragma unroll
      for (int n = 0; n < 2; ++n) {
        int row = wn * 32 + n * 16 + (lane & 15);
        bf16x8 bw = *(bf16x8*)&Wl[row * BK + ((kg ^ (row & 7)) << 3)];
#pragma unroll
        for (int m = 0; m < 4; ++m)
          acc[m][n] = __builtin_amdgcn_mfma_f32_16x16x32_bf16(af[m], bw, acc[m][n], 0, 0, 0);
      }
    }
  }

  const int c16 = lane & 15;
  const int r4  = (lane >> 4) * 4;
#pragma unroll
  for (int m = 0; m < 4; ++m)
#pragma unroll
    for (int n = 0; n < 2; ++n)
#pragma unroll
      for (int r = 0; r < 4; ++r) {
        int b = wm * 64 + m * 16 + r4 + r;
        int d = d0 + wn * 32 + n * 16 + c16;
        out[(size_t)b * (NLAYERS * HID) + (size_t)layer * HID + d] = acc[m][n][r];
      }
}

extern "C" void kernel_launch(void* const* d_in, const int* in_sizes, int n_in,
                              void* d_out, int out_size, void* d_ws, size_t ws_size,
                              hipStream_t stream) {
  const float* h  = (const float*)d_in[0];
  const float* Wg = (const float*)d_in[1];
  const float* Wu = (const float*)d_in[2];
  const float* Wd = (const float*)d_in[3];
  float* out  = (float*)d_out;
  ushort* act = (ushort*)d_ws;                                    // 46.1 MB
  ushort* Xp3 = (ushort*)d_ws + (size_t)NLAYERS * BATCH * INTER;  // +16.8 MB

  hipLaunchKernelGGL(k_pack_frag, dim3(4096), dim3(256), 0, stream, h, Xp3);
  hipLaunchKernelGGL(k_gateup_frag, dim3(NLAYERS * 44), dim3(512), 0, stream,
                     Xp3, Wg, Wu, act);
  hipLaunchKernelGGL(k_down_v4, dim3(NLAYERS * (HID / 64)), dim3(512), 0, stream,
                     act, Wd, out);
}

// Round 15
// 340.518 us; speedup vs baseline: 2.0876x; 1.5971x over previous
//
#include <hip/hip_runtime.h>
#include <hip/hip_bf16.h>

#define BATCH   256
#define NLAYERS 32
#define HID     1024
#define INTER   2816
#define BK      64

typedef __attribute__((ext_vector_type(8))) short bf16x8;
typedef __attribute__((ext_vector_type(4))) float f32x4;
typedef __attribute__((ext_vector_type(4))) int   i32x4;

__device__ __forceinline__ ushort f2bf(float f) {
  __hip_bfloat16 b = __float2bfloat16(f);   // RNE
  return *reinterpret_cast<ushort*>(&b);
}

__device__ __forceinline__ bf16x8 cvt8(f32x4 a, f32x4 b) {
  bf16x8 o;
  o[0] = (short)f2bf(a[0]); o[1] = (short)f2bf(a[1]);
  o[2] = (short)f2bf(a[2]); o[3] = (short)f2bf(a[3]);
  o[4] = (short)f2bf(b[0]); o[5] = (short)f2bf(b[1]);
  o[6] = (short)f2bf(b[2]); o[7] = (short)f2bf(b[3]);
  return o;
}

// ---------------------------------------------------------------------------
// Kernel 0: pack h (B,N,D) fp32 -> Xp[n][b][d] bf16 (contiguous per layer).
// Measured ~10 us.
// ---------------------------------------------------------------------------
__global__ __launch_bounds__(256) void k_pack_f(
    const float* __restrict__ h, ushort* __restrict__ Xp) {
  const int r    = blockIdx.x * 4 + (threadIdx.x >> 6);   // 0..8191 = b*32+n
  const int lane = threadIdx.x & 63;
  const int ro   = ((r & 31) * 256 + (r >> 5)) * 1024;    // out row = n*256+b
  const float* src = h + (size_t)r * 1024 + lane * 4;
  ushort* dst      = Xp + ro + lane * 4;
#pragma unroll
  for (int g = 0; g < 4; ++g) {
    f32x4 v = *(const f32x4*)(src + g * 256);
    ushort4 o;
    o.x = f2bf(v[0]); o.y = f2bf(v[1]); o.z = f2bf(v[2]); o.w = f2bf(v[3]);
    *(ushort4*)(dst + g * 256) = o;
  }
}

// ---------------------------------------------------------------------------
// Kernel 1: act[layer][b][i] = silu(X Wg^T) * (X Wu^T), bf16 -> ws.
// R4 EXACT (measured best of 7 structural variants: 230 us).
// BM=256 (weights from HBM exactly once), BN=32, BK=64, 512 thr, 40 KB LDS,
// XOR swizzle (measured 0 conflicts), 2 barriers/step, 1-deep reg prefetch,
// natural block order (XCD swizzle measured -11%, R12).
// B-tile = 64 rows (0..31 Wg, 32..63 Wu); waves 8M x 1N; per-thread
// acc[m][0..1]=gate, acc[m][2..3]=up for same (b,i) -> silu thread-local.
// ---------------------------------------------------------------------------
__global__ __launch_bounds__(512) void k_gateup_f(
    const ushort* __restrict__ Xp, const float* __restrict__ Wg,
    const float* __restrict__ Wu, ushort* __restrict__ act) {
  const int bid   = blockIdx.x;
  const int layer = bid / (INTER / 32);    // 88 itiles/layer
  const int it    = bid % (INTER / 32);
  const int i0    = it * 32;
  const int tid   = threadIdx.x;
  const int lane  = tid & 63;
  const int wave  = tid >> 6;
  const int m0    = wave * 32;             // wave-exclusive 32 batch rows

  __shared__ ushort lds[BATCH * BK + 64 * BK];   // 40 KiB
  ushort* Al = lds;
  ushort* Wl = lds + BATCH * BK;

  f32x4 acc[2][4] = {};                    // [m][n]; n 0..1 gate, 2..3 up

  // A staging: 2048 granules of 8 bf16; 4 per thread (i32x4 copy, no cvt)
  int aldst[4];
  const ushort* asrc[4];
#pragma unroll
  for (int r = 0; r < 4; ++r) {
    int g = tid + 512 * r;
    int arow = g >> 3, akc = g & 7;
    aldst[r] = arow * BK + ((akc ^ (arow & 7)) << 3);
    asrc[r] = Xp + ((size_t)layer * BATCH + arow) * HID + akc * 8;
  }
  // B staging: row tid>>3 (0..63: <32 -> Wg, >=32 -> Wu), 8 floats at (tid&7)*8
  const int wrow = tid >> 3, wsl = tid & 7;
  const int wldst = wrow * BK + ((wsl ^ (wrow & 7)) << 3);
  const float* wsrc = (wrow < 32 ? Wg + (size_t)(i0 + wrow) * HID
                                 : Wu + (size_t)(i0 + wrow - 32) * HID) +
                      (size_t)layer * INTER * HID + wsl * 8;

  i32x4 ra[4];
  f32x4 rw[2];
#pragma unroll
  for (int r = 0; r < 4; ++r) ra[r] = *(const i32x4*)asrc[r];
  rw[0] = *(const f32x4*)wsrc; rw[1] = *(const f32x4*)(wsrc + 4);

  const int r16 = lane & 15;
  const int g4  = lane >> 4;

  const int NK = HID / BK;                 // 16
  for (int k = 0; k < NK; ++k) {
    __syncthreads();
#pragma unroll
    for (int r = 0; r < 4; ++r) *(i32x4*)&Al[aldst[r]] = ra[r];
    *(bf16x8*)&Wl[wldst] = cvt8(rw[0], rw[1]);
    __syncthreads();

    if (k + 1 < NK) {                      // prefetch t+1 (in flight across MFMA)
      int off = (k + 1) * BK;
#pragma unroll
      for (int r = 0; r < 4; ++r) ra[r] = *(const i32x4*)(asrc[r] + off);
      rw[0] = *(const f32x4*)(wsrc + off); rw[1] = *(const f32x4*)(wsrc + off + 4);
    }

#pragma unroll
    for (int ks = 0; ks < 2; ++ks) {
      const int kg = ks * 4 + g4;
      bf16x8 af[2];
#pragma unroll
      for (int m = 0; m < 2; ++m) {
        int row = m0 + m * 16 + r16;
        af[m] = *(bf16x8*)&Al[row * BK + ((kg ^ (row & 7)) << 3)];
      }
#pragma unroll
      for (int n = 0; n < 4; ++n) {
        int row = n * 16 + r16;
        bf16x8 bw = *(bf16x8*)&Wl[row * BK + ((kg ^ (row & 7)) << 3)];
#pragma unroll
        for (int m = 0; m < 2; ++m)
          acc[m][n] = __builtin_amdgcn_mfma_f32_16x16x32_bf16(af[m], bw, acc[m][n], 0, 0, 0);
      }
    }
  }

  // epilogue: silu(gate)*up, thread-local.  C/D: col=lane&15, row=(lane>>4)*4+r
  const int r4 = (lane >> 4) * 4;
#pragma unroll
  for (int m = 0; m < 2; ++m)
#pragma unroll
    for (int n = 0; n < 2; ++n)
#pragma unroll
      for (int r = 0; r < 4; ++r) {
        float g = acc[m][n][r];
        float u = acc[m][n + 2][r];
        float a = (g / (1.f + __expf(-g))) * u;
        int b = m0 + m * 16 + r4 + r;
        int i = i0 + n * 16 + r16;
        act[((size_t)layer * BATCH + b) * INTER + i] = f2bf(a);
      }
}

// ---------------------------------------------------------------------------
// Kernel 2: out[b][layer][d] = act Wd^T.  R1 exact structure, natural block
// order.  Measured ~65 us (at its roofline).
// ---------------------------------------------------------------------------
__global__ __launch_bounds__(512) void k_down_f(
    const ushort* __restrict__ act, const float* __restrict__ Wd,
    float* __restrict__ out) {
  const int bid   = blockIdx.x;
  const int layer = bid / (HID / 64);
  const int dtile = bid % (HID / 64);
  const int d0    = dtile * 64;
  const int tid   = threadIdx.x;
  const int lane  = tid & 63;
  const int wave  = tid >> 6;
  const int wm    = wave >> 1;
  const int wn    = wave & 1;

  __shared__ ushort lds[BATCH * BK + 64 * BK];       // 40 KiB
  ushort* Al = lds;
  ushort* Wl = lds + BATCH * BK;

  f32x4 acc[4][2] = {};

  int aldst[4];
  const ushort* asrc[4];
#pragma unroll
  for (int r = 0; r < 4; ++r) {
    int g = tid + 512 * r;
    int arow = g >> 3, akc = g & 7;
    aldst[r] = arow * BK + ((akc ^ (arow & 7)) << 3);
    asrc[r] = act + ((size_t)layer * BATCH + arow) * INTER + akc * 8;
  }
  const int wrow = tid >> 3, wkc = tid & 7;
  const int wldst = wrow * BK + ((wkc ^ (wrow & 7)) << 3);
  const float* wsrc = Wd + (size_t)layer * HID * INTER + (size_t)(d0 + wrow) * INTER + wkc * 8;

  i32x4 ra[4];
  f32x4 rw[2];

#pragma unroll
  for (int r = 0; r < 4; ++r) ra[r] = *(const i32x4*)asrc[r];
  rw[0] = *(const f32x4*)wsrc; rw[1] = *(const f32x4*)(wsrc + 4);

  const int NK = INTER / BK;   // 44
  for (int k = 0; k < NK; ++k) {
    __syncthreads();
#pragma unroll
    for (int r = 0; r < 4; ++r) *(i32x4*)&Al[aldst[r]] = ra[r];
    *(bf16x8*)&Wl[wldst] = cvt8(rw[0], rw[1]);
    __syncthreads();

    if (k + 1 < NK) {
      int off = (k + 1) * BK;
#pragma unroll
      for (int r = 0; r < 4; ++r) ra[r] = *(const i32x4*)(asrc[r] + off);
      rw[0] = *(const f32x4*)(wsrc + off); rw[1] = *(const f32x4*)(wsrc + off + 4);
    }

#pragma unroll
    for (int ks = 0; ks < 2; ++ks) {
      const int kg = ks * 4 + (lane >> 4);
      bf16x8 af[4];
#pragma unroll
      for (int m = 0; m < 4; ++m) {
        int row = wm * 64 + m * 16 + (lane & 15);
        af[m] = *(bf16x8*)&Al[row * BK + ((kg ^ (row & 7)) << 3)];
      }
#pragma unroll
      for (int n = 0; n < 2; ++n) {
        int row = wn * 32 + n * 16 + (lane & 15);
        bf16x8 bw = *(bf16x8*)&Wl[row * BK + ((kg ^ (row & 7)) << 3)];
#pragma unroll
        for (int m = 0; m < 4; ++m)
          acc[m][n] = __builtin_amdgcn_mfma_f32_16x16x32_bf16(af[m], bw, acc[m][n], 0, 0, 0);
      }
    }
  }

  const int c16 = lane & 15;
  const int r4  = (lane >> 4) * 4;
#pragma unroll
  for (int m = 0; m < 4; ++m)
#pragma unroll
    for (int n = 0; n < 2; ++n)
#pragma unroll
      for (int r = 0; r < 4; ++r) {
        int b = wm * 64 + m * 16 + r4 + r;
        int d = d0 + wn * 32 + n * 16 + c16;
        out[(size_t)b * (NLAYERS * HID) + (size_t)layer * HID + d] = acc[m][n][r];
      }
}

extern "C" void kernel_launch(void* const* d_in, const int* in_sizes, int n_in,
                              void* d_out, int out_size, void* d_ws, size_t ws_size,
                              hipStream_t stream) {
  const float* h  = (const float*)d_in[0];
  const float* Wg = (const float*)d_in[1];
  const float* Wu = (const float*)d_in[2];
  const float* Wd = (const float*)d_in[3];
  float* out  = (float*)d_out;
  ushort* act = (ushort*)d_ws;                                   // 46.1 MB
  ushort* Xp  = (ushort*)d_ws + (size_t)NLAYERS * BATCH * INTER; // +16.8 MB

  hipLaunchKernelGGL(k_pack_f, dim3(BATCH * NLAYERS / 4), dim3(256), 0, stream,
                     h, Xp);
  hipLaunchKernelGGL(k_gateup_f, dim3(NLAYERS * (INTER / 32)), dim3(512), 0, stream,
                     Xp, Wg, Wu, act);
  hipLaunchKernelGGL(k_down_f, dim3(NLAYERS * (HID / 64)), dim3(512), 0, stream,
                     act, Wd, out);
}